// Round 7
// baseline (123.625 us; speedup 1.0000x reference)
//
#include <hip/hip_runtime.h>

using half2v  = __attribute__((ext_vector_type(2))) _Float16;
using half4   = __attribute__((ext_vector_type(4))) _Float16;
using half8   = __attribute__((ext_vector_type(8))) _Float16;
using floatx4 = __attribute__((ext_vector_type(4))) float;

constexpr int BATCH = 2;
constexpr int NPOS  = 96 * 96;    // 9216
constexpr int NT    = NPOS / 16;  // 576 sixteen-wide i-tiles
constexpr int NST   = NPOS / 32;  // 288 thirty-two-wide j-steps

#define EXP2(x) __builtin_amdgcn_exp2f(x)
#define MFMA16(A, B, C) __builtin_amdgcn_mfma_f32_16x16x16f16(A, B, C, 0, 0, 0)
#define MFMA32(A, B, C) __builtin_amdgcn_mfma_f32_16x16x32_f16(A, B, C, 0, 0, 0)

__device__ inline half8 p8_of(floatx4 e0, floatx4 e1) {
    half2v a0 = __builtin_bit_cast(half2v,
        __builtin_amdgcn_cvt_pkrtz(EXP2(e0[0]), EXP2(e0[1])));
    half2v a1 = __builtin_bit_cast(half2v,
        __builtin_amdgcn_cvt_pkrtz(EXP2(e0[2]), EXP2(e0[3])));
    half2v a2 = __builtin_bit_cast(half2v,
        __builtin_amdgcn_cvt_pkrtz(EXP2(e1[0]), EXP2(e1[1])));
    half2v a3 = __builtin_bit_cast(half2v,
        __builtin_amdgcn_cvt_pkrtz(EXP2(e1[2]), EXP2(e1[3])));
    half8 p = {a0[0], a0[1], a1[0], a1[1], a2[0], a2[1], a3[0], a3[1]};
    return p;
}

// ---------------------------------------------------------------------------
// K1: QKV projection (unchanged).
// ---------------------------------------------------------------------------
__global__ __launch_bounds__(256) void qkv_kernel(
    const float* __restrict__ x,
    const float* __restrict__ wq, const float* __restrict__ bq,
    const float* __restrict__ wk, const float* __restrict__ bk,
    const float* __restrict__ wv, const float* __restrict__ bv,
    _Float16* __restrict__ Qf, _Float16* __restrict__ Kf,
    _Float16* __restrict__ Vf)
{
    __shared__ float W[80][64];
    __shared__ float bias[80];
    __shared__ float qs[32][9];
    __shared__ float ks[32][9];
    __shared__ _Float16 vs[32][72];
    const int tid = threadIdx.x;
    for (int idx = tid; idx < 80 * 64; idx += 256) {
        int o = idx >> 6, c = idx & 63;
        float w;
        if (o < 8)       w = wq[o * 64 + c];
        else if (o < 16) w = wk[(o - 8) * 64 + c];
        else             w = wv[(o - 16) * 64 + c];
        W[o][c] = w;
    }
    if (tid < 80) {
        float bb;
        if (tid < 8)       bb = bq[tid];
        else if (tid < 16) bb = bk[tid - 8];
        else               bb = bv[tid - 16];
        bias[tid] = bb;
    }
    __syncthreads();

    const int js = blockIdx.x;          // 0..287
    const int b  = blockIdx.y;
    const int part = tid >> 5;          // 0..7
    const int jl   = tid & 31;
    const int i    = js * 32 + jl;

    float xr[64];
    #pragma unroll
    for (int c = 0; c < 64; ++c)
        xr[c] = x[(size_t)(b * 64 + c) * NPOS + i];

    #pragma unroll
    for (int q = 0; q < 10; ++q) {
        const int o = part * 10 + q;
        float s = bias[o];
        #pragma unroll
        for (int c4 = 0; c4 < 16; ++c4) {
            float4 w4 = *(const float4*)&W[o][c4 * 4];
            s += w4.x * xr[c4*4+0] + w4.y * xr[c4*4+1]
               + w4.z * xr[c4*4+2] + w4.w * xr[c4*4+3];
        }
        if (o < 8)       qs[jl][o] = s;
        else if (o < 16) ks[jl][o - 8] = s;
        else             vs[jl][o - 16] = (_Float16)s;
    }
    __syncthreads();

    const size_t tile = (size_t)b * NST + js;
    {   // Vf
        const int ct = tid >> 6, l = tid & 63;
        const int g = l >> 4, cl = l & 15;
        half8 o8;
        #pragma unroll
        for (int idx = 0; idx < 8; ++idx)
            o8[idx] = vs[8 * g + idx][16 * ct + cl];
        *(half8*)&Vf[(tile * 256 + ct * 64 + l) * 8] = o8;
    }
    if (tid < 128) {   // Qf (j-permuted, log2e-scaled)
        const int l = tid >> 1, e = tid & 1;
        const int m = l & 15, g = l >> 4;
        const int jsrc = 8 * (m >> 2) + 4 * e + (m & 3);
        constexpr float LOG2E = 1.44269504088896f;
        half4 qh;
        #pragma unroll
        for (int r = 0; r < 4; ++r)
            qh[r] = (g < 2) ? (_Float16)(qs[jsrc][4 * g + r] * LOG2E)
                            : (_Float16)0.f;
        ((half4*)Qf)[(tile * 64 + l) * 2 + e] = qh;
    } else {           // Kf (augment dims d=8,9 -> 1.0; inert vs q_aug = 0)
        const int t = tid - 128;
        const int ht = t >> 6, l = t & 63;
        const int il = l & 15, g = l >> 4;
        const int it = js * 2 + ht;
        half4 kh;
        #pragma unroll
        for (int r = 0; r < 4; ++r) {
            if (g < 2)       kh[r] = (_Float16)ks[16 * ht + il][4 * g + r];
            else if (g == 2) kh[r] = (r < 2) ? (_Float16)1.f : (_Float16)0.f;
            else             kh[r] = (_Float16)0.f;
        }
        ((half4*)Kf)[(size_t)(b * NT + it) * 64 + l] = kh;
    }
}

// ---------------------------------------------------------------------------
// K3: attention, round-7: 2x2 wave split (c-half x j-half) to cut LDS ops.
// Round-6 diagnosis: 20 b128 LDS ops/wave-step saturated the CU-shared LDS
// pipe (~68% busy); all 4 waves re-read the same 16 P fragments.
// Now wave w = (wc = w&1, wj = w>>1): produces jsub w (4 ds_writes), keeps
// own frags in regs, consumes ONLY its 2 c-tiles x 2 jsubs -> 4 ds_reads
// of partner (w^1) frags. 8 LDS ops/wave-step (-60%). Same MFMA/exp/V work.
// P0/P1 are SEPARATE __shared__ arrays with compile-time alternation ->
// provable no-alias -> produce(k+1)/consume(k) truly interleave.
// Epilogue: j-half merge in LDS, then wj=0 waves store; rowsum as before.
// ---------------------------------------------------------------------------
template<int JSPLIT>
__global__ __launch_bounds__(256, 2) void attn_kernel(
    const _Float16* __restrict__ Qf, const _Float16* __restrict__ Kf,
    const _Float16* __restrict__ Vf,
    float* __restrict__ part, float* __restrict__ part_rs)
{
    constexpr int NSTEP = NST / JSPLIT / 4;   // 18 (x4), 36 (x2); even, >=2
    __shared__ half8 P0[4][4][64];       // 16 KB  [jsub][ist][lane]
    __shared__ half8 P1[4][4][64];       // 16 KB
    __shared__ float rsred[4][4][16];    // 1 KB
    const int s   = blockIdx.x;          // 0..287
    const int jh  = blockIdx.y;          // 0..JSPLIT-1
    const int b   = s & 1;
    const int igl = s >> 1;              // 0..143
    const int tid = threadIdx.x;
    const int w = tid >> 6, l = tid & 63;
    const int wc = w & 1, wj = w >> 1;
    const int it0 = igl * 4, i0 = igl * 64;

    const half8* __restrict__ qfb = (const half8*)Qf + (size_t)b * NST * 64;
    const half4* __restrict__ kfb = (const half4*)Kf + (size_t)b * NT * 64;
    const half8* __restrict__ vfb = (const half8*)Vf + (size_t)b * NST * 256;

    half4 kf[4];
    #pragma unroll
    for (int st = 0; st < 4; ++st) kf[st] = kfb[(size_t)(it0 + st) * 64 + l];

    half8 vones;
    #pragma unroll
    for (int e = 0; e < 8; ++e)
        vones[e] = (_Float16)(((l & 15) == 0) ? 1.f : 0.f);

    floatx4 acc[4][2];   // [ist][cti]; this wave's c-tiles = {2wc, 2wc+1}
    floatx4 rs[4];
    #pragma unroll
    for (int st = 0; st < 4; ++st) {
        acc[st][0] = (floatx4){0.f, 0.f, 0.f, 0.f};
        acc[st][1] = (floatx4){0.f, 0.f, 0.f, 0.f};
        rs[st]     = (floatx4){0.f, 0.f, 0.f, 0.f};
    }

    const floatx4 z = {0.f, 0.f, 0.f, 0.f};
    const int st0 = jh * (NST / JSPLIT);

    // pointer-bump addressing (constant offsets inside the loop)
    const half8* qp = qfb + (size_t)(st0 + 8 + w) * 64 + l;   // q(2) prefetch
    const half8* vb = vfb + (size_t)(st0 + 2 * wj) * 256 + wc * 128 + l;
    const int o_own  = wc * 256;        // V offset of own jsub
    const int o_part = 256 - o_own;     // V offset of partner jsub

    half8 qA = qfb[(size_t)(st0 + w) * 64 + l];       // q(0)
    half8 qB = qfb[(size_t)(st0 + 4 + w) * 64 + l];   // q(1)
    half8 pwA[4], pwB[4];

    // ---- prologue: produce(0) -> P0, pwA ----
    {
        half4 qe0 = __builtin_shufflevector(qA, qA, 0, 1, 2, 3);
        half4 qe1 = __builtin_shufflevector(qA, qA, 4, 5, 6, 7);
        #pragma unroll
        for (int ist = 0; ist < 4; ++ist) {
            floatx4 e0 = MFMA16(qe0, kf[ist], z);
            floatx4 e1 = MFMA16(qe1, kf[ist], z);
            half8 pw = p8_of(e0, e1);
            rs[ist] = MFMA32(vones, pw, rs[ist]);
            P0[w][ist][l] = pw;
            pwA[ist] = pw;
        }
    }
    __syncthreads();

    // body(k): consume(k) from PRD+PWOLD+vb; produce(k+1) -> PWR, PWNEW.
    #define BODY(PRD, PWR, PWOLD, PWNEW, QUSE, QPRE) do { \
        half8 pr0 = PRD[w ^ 1][0][l], pr1 = PRD[w ^ 1][1][l]; \
        half8 pr2 = PRD[w ^ 1][2][l], pr3 = PRD[w ^ 1][3][l]; \
        half8 vo0 = vb[o_own],  vo1 = vb[o_own + 64]; \
        half8 vq0 = vb[o_part], vq1 = vb[o_part + 64]; \
        QPRE = qp[0]; qp += 256; \
        half4 qe0 = __builtin_shufflevector(QUSE, QUSE, 0, 1, 2, 3); \
        half4 qe1 = __builtin_shufflevector(QUSE, QUSE, 4, 5, 6, 7); \
        _Pragma("unroll") \
        for (int ist = 0; ist < 4; ++ist) { \
            floatx4 e0 = MFMA16(qe0, kf[ist], z); \
            floatx4 e1 = MFMA16(qe1, kf[ist], z); \
            half8 pw = p8_of(e0, e1); \
            rs[ist] = MFMA32(vones, pw, rs[ist]); \
            PWR[w][ist][l] = pw; \
            PWNEW[ist] = pw; \
        } \
        _Pragma("unroll") \
        for (int ist = 0; ist < 4; ++ist) { \
            acc[ist][0] = MFMA32(vo0, PWOLD[ist], acc[ist][0]); \
            acc[ist][1] = MFMA32(vo1, PWOLD[ist], acc[ist][1]); \
        } \
        acc[0][0] = MFMA32(vq0, pr0, acc[0][0]); \
        acc[0][1] = MFMA32(vq1, pr0, acc[0][1]); \
        acc[1][0] = MFMA32(vq0, pr1, acc[1][0]); \
        acc[1][1] = MFMA32(vq1, pr1, acc[1][1]); \
        acc[2][0] = MFMA32(vq0, pr2, acc[2][0]); \
        acc[2][1] = MFMA32(vq1, pr2, acc[2][1]); \
        acc[3][0] = MFMA32(vq0, pr3, acc[3][0]); \
        acc[3][1] = MFMA32(vq1, pr3, acc[3][1]); \
        vb += 1024; \
        __syncthreads(); \
    } while (0)

    for (int t = 0; t < (NSTEP - 2) / 2; ++t) {
        BODY(P0, P1, pwA, pwB, qB, qA);   // even body
        BODY(P1, P0, pwB, pwA, qA, qB);   // odd body
    }
    BODY(P0, P1, pwA, pwB, qB, qA);       // tail body k = NSTEP-2 (even)
    #undef BODY

    // ---- epilogue: consume(NSTEP-1) from P1 + pwB ----
    {
        half8 pr0 = P1[w ^ 1][0][l], pr1 = P1[w ^ 1][1][l];
        half8 pr2 = P1[w ^ 1][2][l], pr3 = P1[w ^ 1][3][l];
        half8 vo0 = vb[o_own],  vo1 = vb[o_own + 64];
        half8 vq0 = vb[o_part], vq1 = vb[o_part + 64];
        #pragma unroll
        for (int ist = 0; ist < 4; ++ist) {
            acc[ist][0] = MFMA32(vo0, pwB[ist], acc[ist][0]);
            acc[ist][1] = MFMA32(vo1, pwB[ist], acc[ist][1]);
        }
        acc[0][0] = MFMA32(vq0, pr0, acc[0][0]);
        acc[0][1] = MFMA32(vq1, pr0, acc[0][1]);
        acc[1][0] = MFMA32(vq0, pr1, acc[1][0]);
        acc[1][1] = MFMA32(vq1, pr1, acc[1][1]);
        acc[2][0] = MFMA32(vq0, pr2, acc[2][0]);
        acc[2][1] = MFMA32(vq1, pr2, acc[2][1]);
        acc[3][0] = MFMA32(vq0, pr3, acc[3][0]);
        acc[3][1] = MFMA32(vq1, pr3, acc[3][1]);
    }
    __syncthreads();   // all P0/P1 traffic done; safe to reuse P0 for merge

    // ---- j-half merge (wj=1 -> LDS; wj=0 adds) + rowsum publish ----
    float4* mrg = (float4*)&P0[0][0][0];   // [2][8][64] float4 = 16 KB
    if (wj == 1) {
        #pragma unroll
        for (int ist = 0; ist < 4; ++ist)
            #pragma unroll
            for (int cti = 0; cti < 2; ++cti)
                mrg[(size_t)((wc * 8 + ist * 2 + cti) * 64) + l] =
                    *(float4*)&acc[ist][cti];
    }
    if (l < 16) {
        #pragma unroll
        for (int ist = 0; ist < 4; ++ist) rsred[w][ist][l] = rs[ist][0];
    }
    __syncthreads();

    float* __restrict__ P  = part    + (size_t)jh * ((size_t)BATCH * 64 * NPOS);
    float* __restrict__ Pr = part_rs + (size_t)jh * ((size_t)BATCH * NPOS);
    if (wj == 0) {
        const int iq = i0 + (l & 15);
        #pragma unroll
        for (int ist = 0; ist < 4; ++ist)
            #pragma unroll
            for (int cti = 0; cti < 2; ++cti) {
                float4 m = mrg[(size_t)((wc * 8 + ist * 2 + cti) * 64) + l];
                float4 a = *(float4*)&acc[ist][cti];
                a.x += m.x; a.y += m.y; a.z += m.z; a.w += m.w;
                #pragma unroll
                for (int r = 0; r < 4; ++r) {
                    int c = 16 * (2 * wc + cti) + 4 * (l >> 4) + r;
                    size_t o = ((size_t)(b * 64 + c)) * NPOS + iq + 16 * ist;
                    P[o] = (&a.x)[r];
                }
            }
    }
    if (w == 0 && l < 16) {
        #pragma unroll
        for (int ist = 0; ist < 4; ++ist) {
            float rsv = rsred[0][ist][l] + rsred[1][ist][l]
                      + rsred[2][ist][l] + rsred[3][ist][l];
            Pr[(size_t)b * NPOS + i0 + 16 * ist + l] = rsv;
        }
    }
}

// ---------------------------------------------------------------------------
// K4: combine epilogue — out = gamma * sum(PV) / sum(rowsum) + x.
// ---------------------------------------------------------------------------
template<int JSPLIT>
__global__ __launch_bounds__(256) void combine_kernel(
    const float* __restrict__ part, const float* __restrict__ part_rs,
    const float* __restrict__ x, const float* __restrict__ gamma,
    float* __restrict__ out)
{
    const float g = gamma[0];
    const size_t idx = (size_t)blockIdx.x * 256 + threadIdx.x; // 0..73727
    const size_t stride  = ((size_t)BATCH * 64 * NPOS) / 4;    // PV f4/jh
    const size_t rstride = ((size_t)BATCH * NPOS) / 4;         // rs f4/jh
    const int i4 = (int)(idx % (NPOS / 4));
    const int b  = (int)(idx / ((size_t)64 * (NPOS / 4)));
    const float4* p0 = (const float4*)part;
    const float4* r0 = (const float4*)part_rs;

    float4 a = p0[idx];
    float4 rsum = r0[(size_t)b * (NPOS / 4) + i4];
    #pragma unroll
    for (int u = 1; u < JSPLIT; ++u) {
        float4 q = p0[idx + (size_t)u * stride];
        a.x += q.x; a.y += q.y; a.z += q.z; a.w += q.w;
        float4 rq = r0[(size_t)b * (NPOS / 4) + i4 + (size_t)u * rstride];
        rsum.x += rq.x; rsum.y += rq.y; rsum.z += rq.z; rsum.w += rq.w;
    }
    float4 xv = ((const float4*)x)[idx];
    float4 o;
    o.x = g * (a.x / rsum.x) + xv.x;
    o.y = g * (a.y / rsum.y) + xv.y;
    o.z = g * (a.z / rsum.z) + xv.z;
    o.w = g * (a.w / rsum.w) + xv.w;
    ((float4*)out)[idx] = o;
}

// ---------------------------------------------------------------------------
extern "C" void kernel_launch(void* const* d_in, const int* in_sizes, int n_in,
                              void* d_out, int out_size, void* d_ws, size_t ws_size,
                              hipStream_t stream)
{
    const float* x     = (const float*)d_in[0];
    const float* wq    = (const float*)d_in[1];
    const float* bq    = (const float*)d_in[2];
    const float* wk    = (const float*)d_in[3];
    const float* bk    = (const float*)d_in[4];
    const float* wv    = (const float*)d_in[5];
    const float* bv    = (const float*)d_in[6];
    const float* gamma = (const float*)d_in[7];
    float* out = (float*)d_out;

    char* wsb = (char*)d_ws;
    _Float16* Qf = (_Float16*)wsb;                       //   589,824 B
    _Float16* Kf = (_Float16*)(wsb + 589824);            //   589,824 B
    _Float16* Vf = (_Float16*)(wsb + 1179648);           // 2,359,296 B
    float*    Pp = (float*)(wsb + 3538944);              // JSPLIT x 4,718,592 B

    qkv_kernel<<<dim3(NST, BATCH), 256, 0, stream>>>(
        x, wq, bq, wk, bk, wv, bv, Qf, Kf, Vf);

    const size_t partBytes = (size_t)BATCH * 64 * NPOS * sizeof(float);
    const size_t rsBytes   = (size_t)BATCH * NPOS * sizeof(float);
    const size_t need4 = 3538944 + 4 * (partBytes + rsBytes); // 22,708,224 B
    const int nblk = (BATCH * 64 * NPOS / 4) / 256; // 1152

    if (ws_size >= need4) {
        float* Prs = (float*)(wsb + 3538944 + 4 * partBytes);
        attn_kernel<4><<<dim3(NST, 4), 256, 0, stream>>>(Qf, Kf, Vf, Pp, Prs);
        combine_kernel<4><<<nblk, 256, 0, stream>>>(Pp, Prs, x, gamma, out);
    } else {
        float* Prs = (float*)(wsb + 3538944 + 2 * partBytes);
        attn_kernel<2><<<dim3(NST, 2), 256, 0, stream>>>(Qf, Kf, Vf, Pp, Prs);
        combine_kernel<2><<<nblk, 256, 0, stream>>>(Pp, Prs, x, gamma, out);
    }
}